// Round 8
// baseline (58.471 us; speedup 1.0000x reference)
//
#include <hip/hip_runtime.h>
#include <hip/hip_bf16.h>

typedef __attribute__((ext_vector_type(8))) short bf16x8;
typedef __attribute__((ext_vector_type(4))) float f32x4;

#define D_K    256
#define WH     784
#define WHH    392
#define P_REAL 511
#define P_PAD  512
#define C_OUT  200
#define NLEAF  512
#define TDEPTH 9

#define NT      32
#define NTILES  13          // 13*32 >= 392 (tail clamped to duplicate columns)
#define TILE_USH 8192       // 32 n x 256 k ushorts = 16 KB

// workspace offsets (bytes)
#define WS_PB   0                          // 512*256*2   = 262144
#define WS_P2   262144                     // 512*4
#define WS_DS   264192                     // 512*200*4
#define WS_PM   673792                     // 128*2*512*4
// total 1198080

static __device__ __forceinline__ unsigned short f2bf(float x) {
    union { float f; unsigned int u; } v; v.f = x;
    unsigned int r = v.u + 0x7FFFu + ((v.u >> 16) & 1u);   // RNE
    return (unsigned short)(r >> 16);
}

// --- fused prep (proto -> bf16(-2p) + p2) and softmax(leaf_params) --------
__global__ __launch_bounds__(64)
void prep2_kernel(const float* __restrict__ protos, const float* __restrict__ lp,
                  unsigned short* __restrict__ pb, float* __restrict__ p2,
                  float* __restrict__ ds) {
    int bid = blockIdx.x;
    int l = threadIdx.x;
    if (bid < P_PAD) {
        int p = bid;
        f32x4 v = {0.f, 0.f, 0.f, 0.f};
        if (p < P_REAL)
            v = *reinterpret_cast<const f32x4*>(protos + (size_t)p * D_K + 4 * l);
        ushort4 w;
        w.x = f2bf(-2.f * v[0]); w.y = f2bf(-2.f * v[1]);
        w.z = f2bf(-2.f * v[2]); w.w = f2bf(-2.f * v[3]);
        *reinterpret_cast<ushort4*>(pb + (size_t)p * D_K + 4 * l) = w;
        float s = v[0]*v[0] + v[1]*v[1] + v[2]*v[2] + v[3]*v[3];
#pragma unroll
        for (int m = 32; m >= 1; m >>= 1) s += __shfl_xor(s, m, 64);
        if (l == 0) p2[p] = s;
    } else {
        int row = bid - P_PAD;
        float v[4];
        float mx = -3.4e38f;
#pragma unroll
        for (int i = 0; i < 4; ++i) {
            int c = l + 64 * i;
            v[i] = (c < C_OUT) ? lp[(size_t)row * C_OUT + c] : -3.4e38f;
            mx = fmaxf(mx, v[i]);
        }
#pragma unroll
        for (int m = 32; m >= 1; m >>= 1) mx = fmaxf(mx, __shfl_xor(mx, m, 64));
        float sum = 0.f;
#pragma unroll
        for (int i = 0; i < 4; ++i) {
            int c = l + 64 * i;
            if (c < C_OUT) { v[i] = expf(v[i] - mx); sum += v[i]; }
        }
#pragma unroll
        for (int m = 32; m >= 1; m >>= 1) sum += __shfl_xor(sum, m, 64);
        float inv = 1.f / sum;
#pragma unroll
        for (int i = 0; i < 4; ++i) {
            int c = l + 64 * i;
            if (c < C_OUT) ds[(size_t)row * C_OUT + c] = v[i] * inv;
        }
    }
}

// --- main: read-once fused distance+min, phase-interleaved ---------------
// grid 256 = 128 b x 2 wh-halves, 512 threads (8 waves), 1 block/CU.
// Each wave holds 64 p-rows (af[4][8]); 8 waves = all 512 protos -> each
// block streams its xs half exactly once. Per tile: two 32-MFMA bursts with
// the next tile's STAGE sandwiched between them (wave-skew overlap), ONE
// barrier per tile, double-buffered LDS.
__global__ __launch_bounds__(512, 2)
void proto_min_kernel(const float* __restrict__ xs,
                      const unsigned short* __restrict__ pb,
                      float* __restrict__ pm) {
    __shared__ unsigned short Xs[2][TILE_USH];     // 32 KB
    __shared__ float x2buf[2][8*68 + 8];           // bank-padded

    const int tid  = threadIdx.x;
    const int wv   = tid >> 6;    // 0..7
    const int lane = tid & 63;
    const int g    = lane >> 4;   // 0..3
    const int lr   = lane & 15;   // 0..15

    const int b   = blockIdx.x >> 1;
    const int whh = blockIdx.x & 1;

    const float* xb = xs + (size_t)b * (D_K * WH) + whh * WHH;

    // A fragments: -2*proto bf16, 64 rows x full K per wave
    bf16x8 af[4][8];
#pragma unroll
    for (int mf = 0; mf < 4; ++mf) {
        const unsigned short* rp = pb + (size_t)(64*wv + 16*mf + lr) * D_K + 8*g;
#pragma unroll
        for (int ks = 0; ks < 8; ++ks)
            af[mf][ks] = *reinterpret_cast<const bf16x8*>(rp + 32*ks);
    }

    const int n4 = tid & 7;    // col-quad within tile (8 quads x 4 cols)
    const int kq = tid >> 3;   // 0..63  (k-quad; 512 threads cover all 256 k)

    float rmin[4][4];
#pragma unroll
    for (int mf = 0; mf < 4; ++mf)
#pragma unroll
        for (int r = 0; r < 4; ++r) rmin[mf][r] = 3.0e38f;

    f32x4 ld[4];   // 16 floats: 4 k-rows x 4 cols

#define LOAD_TILE(T) do {                                                     \
        int colb = (T) * NT + 4 * n4;                                         \
        if (colb > WHH - 4) colb = WHH - 4;                                   \
        const float* rowp = xb + (size_t)(4*kq) * WH + colb;                  \
        _Pragma("unroll")                                                     \
        for (int r = 0; r < 4; ++r)                                           \
            ld[r] = *reinterpret_cast<const f32x4*>(rowp + r * WH);           \
    } while (0)

// element (n,k): ushort offset n*256 + ((kg ^ (n&7))<<3) + (k&7), kg=k>>3
#define STAGE_TILE(DST) do {                                                  \
        f32x4 x2a = {0.f, 0.f, 0.f, 0.f};                                     \
        _Pragma("unroll")                                                     \
        for (int r = 0; r < 4; ++r) {                                         \
            f32x4 v = ld[r];                                                  \
            x2a[0] += v[0]*v[0]; x2a[1] += v[1]*v[1];                         \
            x2a[2] += v[2]*v[2]; x2a[3] += v[3]*v[3];                         \
        }                                                                     \
        _Pragma("unroll")                                                     \
        for (int c = 0; c < 4; ++c) {                                         \
            int n = 4*n4 + c;                                                 \
            float2 f01 = make_float2(ld[0][c], ld[1][c]);                     \
            float2 f23 = make_float2(ld[2][c], ld[3][c]);                     \
            __hip_bfloat162 b01 = __float22bfloat162_rn(f01);                 \
            __hip_bfloat162 b23 = __float22bfloat162_rn(f23);                 \
            uint2 w;                                                          \
            w.x = *reinterpret_cast<unsigned int*>(&b01);                     \
            w.y = *reinterpret_cast<unsigned int*>(&b23);                     \
            int off = n*256 + (((kq >> 1) ^ (n & 7)) << 3) + ((kq & 1) << 2); \
            *reinterpret_cast<uint2*>(&Xs[DST][off]) = w;                     \
        }                                                                     \
        _Pragma("unroll")                                                     \
        for (int c = 0; c < 4; ++c) {                                         \
            x2a[c] += __shfl_xor(x2a[c], 8, 64);                              \
            x2a[c] += __shfl_xor(x2a[c], 16, 64);                             \
            x2a[c] += __shfl_xor(x2a[c], 32, 64);                             \
        }                                                                     \
        if (lane < 8) {                                                       \
            _Pragma("unroll")                                                 \
            for (int c = 0; c < 4; ++c)                                       \
                x2buf[DST][lane*68 + c*8 + wv] = x2a[c];                      \
        }                                                                     \
    } while (0)

// x2 for this lane's column (n = 16*NF + lr): 8 wave-partials
#define X2_READ(NF, OUT) do {                                                 \
        int n = 16*(NF) + lr;                                                 \
        const float* xp = &x2buf[buf][(n >> 2)*68 + (n & 3)*8];               \
        f32x4 q0 = *reinterpret_cast<const f32x4*>(xp);                       \
        f32x4 q1 = *reinterpret_cast<const f32x4*>(xp + 4);                   \
        OUT = ((q0[0]+q0[1]) + (q0[2]+q0[3]))                                 \
            + ((q1[0]+q1[1]) + (q1[2]+q1[3]));                                \
    } while (0)

// one nf-burst: 8 ks x 4 mf MFMAs on column group NF into ACC[4]
#define BURST(NF, ACC) do {                                                   \
        __builtin_amdgcn_s_setprio(1);                                        \
        _Pragma("unroll")                                                     \
        for (int ks = 0; ks < 8; ++ks) {                                      \
            int n = 16*(NF) + lr;                                             \
            int off = n*256 + ((((ks << 2) + g) ^ (n & 7)) << 3);             \
            bf16x8 bfr = *reinterpret_cast<const bf16x8*>(&Xs[buf][off]);     \
            _Pragma("unroll")                                                 \
            for (int mf = 0; mf < 4; ++mf)                                    \
                ACC[mf] = __builtin_amdgcn_mfma_f32_16x16x32_bf16(            \
                    af[mf][ks], bfr, ACC[mf], 0, 0, 0);                       \
        }                                                                     \
        __builtin_amdgcn_s_setprio(0);                                        \
    } while (0)

#define MIN_UPD(ACC) do {                                                     \
        _Pragma("unroll")                                                     \
        for (int mf = 0; mf < 4; ++mf)                                        \
            _Pragma("unroll")                                                 \
            for (int r = 0; r < 4; ++r)                                       \
                rmin[mf][r] = fminf(rmin[mf][r], ACC[mf][r]);                 \
    } while (0)

    // prologue: stage tile 0 into buffer 0
    LOAD_TILE(0);
    STAGE_TILE(0);
    __syncthreads();

    int buf = 0;
    f32x4 acc0[4], acc1[4];

    for (int t = 0; t < NTILES - 1; ++t) {
        // issue next tile's loads first; latency hides under burst0
        LOAD_TILE(t + 1);

        float x2v0; X2_READ(0, x2v0);
#pragma unroll
        for (int mf = 0; mf < 4; ++mf)
            acc0[mf] = (f32x4){x2v0, x2v0, x2v0, x2v0};

        BURST(0, acc0);          // 32 MFMA on nf=0
        MIN_UPD(acc0);           // retire acc0 before the stage window

        STAGE_TILE(buf ^ 1);     // vmcnt drain + cvt + LDS writes mid-tile

        float x2v1; X2_READ(1, x2v1);
#pragma unroll
        for (int mf = 0; mf < 4; ++mf)
            acc1[mf] = (f32x4){x2v1, x2v1, x2v1, x2v1};

        BURST(1, acc1);          // 32 MFMA on nf=1
        MIN_UPD(acc1);

        __syncthreads();
        buf ^= 1;
    }

    // final tile: no load/stage
    {
        float x2v0; X2_READ(0, x2v0);
#pragma unroll
        for (int mf = 0; mf < 4; ++mf)
            acc0[mf] = (f32x4){x2v0, x2v0, x2v0, x2v0};
        BURST(0, acc0);
        MIN_UPD(acc0);

        float x2v1; X2_READ(1, x2v1);
#pragma unroll
        for (int mf = 0; mf < 4; ++mf)
            acc1[mf] = (f32x4){x2v1, x2v1, x2v1, x2v1};
        BURST(1, acc1);
        MIN_UPD(acc1);
    }

    // min across the 16 column-lanes (flips only lr bits; g preserved)
#pragma unroll
    for (int mf = 0; mf < 4; ++mf)
#pragma unroll
        for (int r = 0; r < 4; ++r) {
            float v = rmin[mf][r];
#pragma unroll
            for (int m = 1; m <= 8; m <<= 1)
                v = fminf(v, __shfl_xor(v, m, 64));
            rmin[mf][r] = v;
        }

    if (lr == 0) {
        float* pmw = pm + ((size_t)b * 2 + whh) * P_PAD;
#pragma unroll
        for (int mf = 0; mf < 4; ++mf)
#pragma unroll
            for (int r = 0; r < 4; ++r)
                pmw[64*wv + 16*mf + 4*g + r] = rmin[mf][r];
    }
#undef LOAD_TILE
#undef STAGE_TILE
#undef X2_READ
#undef BURST
#undef MIN_UPD
}

// --- combine halves + exp(-sqrt) + tree path products + pa @ ds -----------
__global__ __launch_bounds__(256)
void out_kernel(const float* __restrict__ pm, const float* __restrict__ p2,
                const float* __restrict__ ds, float* __restrict__ out) {
    __shared__ float sim[NLEAF];
    __shared__ float pa[NLEAF];
    int b = blockIdx.x;
    int t = threadIdx.x;
    const float* pm0 = pm + (size_t)b * 2 * P_PAD;
#pragma unroll
    for (int j = 0; j < 2; ++j) {
        int p = t + 256 * j;
        float m = fminf(pm0[p], pm0[P_PAD + p]);
        float sq = m + p2[p];
        sim[p] = expf(-sqrtf(fabsf(sq) + 1e-14f));
    }
    __syncthreads();
#pragma unroll
    for (int j = 0; j < 2; ++j) {
        int leaf = t + 256 * j;
        int node = 0;
        float prod = 1.f;
#pragma unroll
        for (int st = 0; st < TDEPTH; ++st) {
            int bit = (leaf >> (TDEPTH - 1 - st)) & 1;
            float sv = sim[node];
            prod *= bit ? sv : (1.f - sv);
            node = 2 * node + 1 + bit;
        }
        pa[leaf] = prod;
    }
    __syncthreads();
    if (t < C_OUT) {
        float a0 = 0.f, a1 = 0.f, a2 = 0.f, a3 = 0.f;
        for (int l = 0; l < NLEAF; l += 4) {
            a0 += pa[l + 0] * ds[(size_t)(l + 0) * C_OUT + t];
            a1 += pa[l + 1] * ds[(size_t)(l + 1) * C_OUT + t];
            a2 += pa[l + 2] * ds[(size_t)(l + 2) * C_OUT + t];
            a3 += pa[l + 3] * ds[(size_t)(l + 3) * C_OUT + t];
        }
        out[(size_t)b * C_OUT + t] = (a0 + a1) + (a2 + a3);
    }
}

extern "C" void kernel_launch(void* const* d_in, const int* in_sizes, int n_in,
                              void* d_out, int out_size, void* d_ws, size_t ws_size,
                              hipStream_t stream) {
    (void)in_sizes; (void)n_in; (void)out_size; (void)ws_size;
    const float* xs     = (const float*)d_in[0];
    const float* protos = (const float*)d_in[1];
    const float* lp     = (const float*)d_in[2];
    float* out = (float*)d_out;

    char* ws = (char*)d_ws;
    unsigned short* pb = (unsigned short*)(ws + WS_PB);
    float* p2   = (float*)(ws + WS_P2);
    float* dsm  = (float*)(ws + WS_DS);
    float* pm   = (float*)(ws + WS_PM);

    prep2_kernel<<<1024, 64, 0, stream>>>(protos, lp, pb, p2, dsm);
    proto_min_kernel<<<256, 512, 0, stream>>>(xs, pb, pm);
    out_kernel<<<128, 256, 0, stream>>>(pm, p2, dsm, out);
}